// Round 14
// baseline (333.257 us; speedup 1.0000x reference)
//
#include <hip/hip_runtime.h>
#include <hip/hip_bf16.h>

// Conv2d NCHW, stride=1, pad=1, N=16, C=8, K=8, H=W=1024, 3x3, fp32 in/out.
// Round 14: depth-2 counted-vmcnt pipeline. Every prior round drained vmcnt
// to 0 each iteration (explicitly or via __syncthreads' implicit full drain)
// -> convoy: all blocks stall on staging together, memory idles between
// bursts (steady fetch 1.7 TB/s with NOTHING saturated, r11/r13). Fix per
// T3/T4: double-buffer fp32 AND bf16 LDS, raw s_barrier + counted
// s_waitcnt vmcnt(8) (drains only tile k+1's DMA, leaves the 8 stores),
// DMA for tile k+2 stays in flight across transpose+compute. 256-thr/4-wave
// blocks kept (r12's 8-wave race avoided). Math byte-identical to r13.

typedef __attribute__((ext_vector_type(8))) short short8;
typedef __attribute__((ext_vector_type(4))) float f32x4;

#define HH 1024
#define WW 1024
#define HWsz (1024*1024)
#define WB 64           // output cols per tile
#define HB 8            // output rows per tile
#define SROWS 10        // staged input rows per tile
#define UROW 72         // bf16 16B-units per row (w0-4 .. w0+67)
#define FPITCH 576      // fp32 floats per staged row
#define NIT 32          // h-tiles per block (strip = 256 rows)
#define NSITES (SROWS*UROW)   // 720

__device__ __forceinline__ int pk2(float a, float b) {
    __hip_bfloat162 h = __float22bfloat162_rn(make_float2(a, b));  // v_cvt_pk_bf16_f32
    return *reinterpret_cast<int*>(&h);
}
__device__ __forceinline__ unsigned short f2bf(float f) {
    unsigned u = __float_as_uint(f);
    return (unsigned short)((u + 0x7FFFu + ((u >> 16) & 1u)) >> 16);   // RNE
}
__device__ __forceinline__ void gl_lds16(const float* g, float* l) {
    __builtin_amdgcn_global_load_lds(
        (const __attribute__((address_space(1))) void*)g,
        (__attribute__((address_space(3))) void*)l, 16, 0, 0);
}

__global__ __launch_bounds__(256) void conv3x3_pipe2(
    const float* __restrict__ x,      // [16][8][1024][1024]
    const float* __restrict__ wgt,    // [8][8][3][3]
    const float* __restrict__ bias,   // [8]
    float* __restrict__ out)          // [16][8][1024][1024]
{
    __shared__ float fpA[SROWS * FPITCH];     // 23040 B each
    __shared__ float fpB[SROWS * FPITCH];
    __shared__ int4  bfA[NSITES];             // 11520 B each
    __shared__ int4  bfB[NSITES];

    const int tid  = threadIdx.x;
    const int lane = tid & 63;
    const int wv   = tid >> 6;        // wave 0..3
    const int l15  = lane & 15;
    const int ch   = lane >> 4;

    const int wx    = blockIdx.x;     // 0..15
    const int strip = blockIdx.y;     // 0..3
    const int n     = blockIdx.z;     // 0..15
    const int w0    = wx * WB;
    const int htbase = strip * (NIT * HB);    // strip*256

    const float* xn = x + (size_t)n * 8 * HWsz;

    // ---- tap -> bf16-LDS unit offsets (verified r7/r8/r11/r13) ----
    const int t0  = ch;                       // taps 0..3 (MFMA 0)
    const int kh0 = (t0 >= 3) ? 1 : 0;
    const int kw0 = t0 - 3 * kh0;
    const int t1  = 4 + ch;                   // taps 4..7 (MFMA 1)
    const int kh1 = (t1 >= 6) ? 2 : 1;
    const int kw1 = t1 - 3 * kh1;
    const int off0 = kh0 * UROW + kw0 + 3;
    const int off1 = kh1 * UROW + kw1 + 3;
    const int off2 = 2 * UROW + 2 + 3;        // tap 8 (2,2)

    // ---- weight B-fragments (verified) ----
    const int  coc = (l15 < 8) ? l15 : 7;
    const bool com = (l15 < 8);
    short8 b0, b1, b2;
    {
        const float* wp0 = wgt + coc * 72 + kh0 * 3 + kw0;
        const float* wp1 = wgt + coc * 72 + kh1 * 3 + kw1;
        const float* wp2 = wgt + coc * 72 + 2 * 3 + 2;
#pragma unroll
        for (int j = 0; j < 8; ++j) {
            b0[j] = (short)(com ? f2bf(wp0[j * 9]) : 0);
            b1[j] = (short)(com ? f2bf(wp1[j * 9]) : 0);
            b2[j] = (short)((com && ch == 0) ? f2bf(wp2[j * 9]) : 0);
        }
    }
    const float bv = com ? bias[l15] : 0.0f;

    // ---- staging lane constants ----
    const int sci_f = lane >> 3;      // full instr: ci = lane/8
    const int swg_f = lane & 7;       //             wgrp = lane%8
    const int sci_p = lane >> 1;      // partial instr: ci = lane/2
    const int swg_p = lane & 1;

    // DMA count per wave: wv<2 -> 3 rows * 3 instrs = 9; else 2*3 = 6.
    auto STAGE = [&](int htile, float* fpb) {
        int rows[3];
        rows[0] = 2 * wv; rows[1] = 2 * wv + 1; rows[2] = 8 + wv;
        const int nr = (wv < 2) ? 3 : 2;
        for (int i = 0; i < nr; ++i) {
            const int row = rows[i];                  // wave-uniform
            int gh = htile - 1 + row;
            gh = (gh < 0) ? 0 : ((gh > HH - 1) ? HH - 1 : gh);
            const float* rowf = xn + (size_t)sci_f * HWsz + (size_t)gh * WW;
#pragma unroll
            for (int q = 0; q < 2; ++q) {             // 2 full instrs (u 0..63)
                int gs = w0 - 4 + (q * 8 + swg_f) * 4;
                gs = (gs < 0) ? 0 : ((gs > WW - 4) ? WW - 4 : gs);
                gl_lds16(rowf + gs, &fpb[row * FPITCH + q * 256]);
            }
            {                                         // partial instr (u 64..71)
                const float* rowp = xn + (size_t)sci_p * HWsz + (size_t)gh * WW;
                int gs = w0 - 4 + (16 + swg_p) * 4;
                gs = (gs > WW - 4) ? WW - 4 : gs;
                if (lane < 16) gl_lds16(rowp + gs, &fpb[row * FPITCH + 512]);
            }
        }
    };

    auto TRANS = [&](int htile, const float* fpb, int4* bfb) {
        for (int s = tid; s < NSITES; s += 256) {
            const int row = s / UROW;
            const int u   = s - row * UROW;
            const int gh  = htile - 1 + row;
            const int gw  = w0 - 4 + u;
            const bool ok = ((unsigned)gh < (unsigned)HH) &&
                            ((unsigned)gw < (unsigned)WW);
            int fbase, cs;
            if (u < 64) {
                fbase = row * FPITCH + (u >> 5) * 256 + ((u >> 2) & 7) * 4 + (u & 3);
                cs = 32;
            } else {
                fbase = row * FPITCH + 512 + ((u >> 2) & 1) * 4 + (u & 3);
                cs = 8;
            }
            float v0 = ok ? fpb[fbase]          : 0.0f;
            float v1 = ok ? fpb[fbase + 1 * cs] : 0.0f;
            float v2 = ok ? fpb[fbase + 2 * cs] : 0.0f;
            float v3 = ok ? fpb[fbase + 3 * cs] : 0.0f;
            float v4 = ok ? fpb[fbase + 4 * cs] : 0.0f;
            float v5 = ok ? fpb[fbase + 5 * cs] : 0.0f;
            float v6 = ok ? fpb[fbase + 6 * cs] : 0.0f;
            float v7 = ok ? fpb[fbase + 7 * cs] : 0.0f;
            int4 pk;
            pk.x = pk2(v0, v1);
            pk.y = pk2(v2, v3);
            pk.z = pk2(v4, v5);
            pk.w = pk2(v6, v7);
            bfb[s] = pk;
        }
    };

    // ---- prologue: stage tiles 0,1; full drain ONCE; transpose tile 0 ----
    STAGE(htbase, fpA);
    STAGE(htbase + HB, fpB);
    asm volatile("s_waitcnt vmcnt(0)" ::: "memory");
    __builtin_amdgcn_sched_barrier(0);
    __builtin_amdgcn_s_barrier();
    TRANS(htbase, fpA, bfA);
    asm volatile("s_waitcnt lgkmcnt(0)" ::: "memory");
    __builtin_amdgcn_sched_barrier(0);
    __builtin_amdgcn_s_barrier();

    // ---- steady-state loop: never drain vmcnt to 0 ----
    for (int k = 0; k < NIT; ++k) {
        const int htile = htbase + k * HB;

        // 1. drain ONLY tile k+1's DMA (oldest S ops); 8 stores may remain
        asm volatile("s_waitcnt vmcnt(8)" ::: "memory");
        __builtin_amdgcn_sched_barrier(0);
        __builtin_amdgcn_s_barrier();

        // 2. transpose tile k+1 into the other bf buffer
        {
            const float* fsrc = ((k + 1) & 1) ? fpB : fpA;
            int4*        bdst = ((k + 1) & 1) ? bfB : bfA;
            TRANS(htile + HB, fsrc, bdst);   // last iter: writes unread buf (safe)
        }
        asm volatile("s_waitcnt lgkmcnt(0)" ::: "memory");
        __builtin_amdgcn_sched_barrier(0);
        __builtin_amdgcn_s_barrier();

        // 3. stage tile k+2 (clamped; uniform DMA count) into fp[k&1]
        {
            int t2 = k + 2; if (t2 > NIT - 1) t2 = NIT - 1;
            STAGE(htbase + t2 * HB, (k & 1) ? fpB : fpA);
        }

        // 4. compute tile k from bf[k&1] + stores (8 store instrs per wave)
        const int4* bsrc = (k & 1) ? bfB : bfA;
        f32x4 acc[2][4];
#pragma unroll
        for (int th = 0; th < 2; ++th)
#pragma unroll
            for (int wt = 0; wt < 4; ++wt) {
                acc[th][wt].x = bv; acc[th][wt].y = bv;
                acc[th][wt].z = bv; acc[th][wt].w = bv;
            }
#pragma unroll
        for (int th = 0; th < 2; ++th) {
            const int hl = wv * 2 + th;
            const int ub = hl * UROW + l15;
#pragma unroll
            for (int wt = 0; wt < 4; ++wt) {
                const int u = ub + wt * 16;
                short8 a0 = *reinterpret_cast<const short8*>(&bsrc[u + off0]);
                short8 a1 = *reinterpret_cast<const short8*>(&bsrc[u + off1]);
                short8 a2 = *reinterpret_cast<const short8*>(&bsrc[u + off2]);
                f32x4 c = acc[th][wt];
                c = __builtin_amdgcn_mfma_f32_16x16x32_bf16(a0, b0, c, 0, 0, 0);
                c = __builtin_amdgcn_mfma_f32_16x16x32_bf16(a1, b1, c, 0, 0, 0);
                c = __builtin_amdgcn_mfma_f32_16x16x32_bf16(a2, b2, c, 0, 0, 0);
                acc[th][wt] = c;
            }
        }
        if (com) {
#pragma unroll
            for (int th = 0; th < 2; ++th) {
                const int hl = wv * 2 + th;
                float* op = out + ((size_t)n * 8 + l15) * HWsz
                                + (size_t)(htile + hl) * WW + w0 + ch * 4;
#pragma unroll
                for (int wt = 0; wt < 4; ++wt)
                    *reinterpret_cast<float4*>(op + wt * 16) =
                        *reinterpret_cast<const float4*>(&acc[th][wt]);
            }
        }
    }
}

extern "C" void kernel_launch(void* const* d_in, const int* in_sizes, int n_in,
                              void* d_out, int out_size, void* d_ws, size_t ws_size,
                              hipStream_t stream) {
    const float* x    = (const float*)d_in[0];
    const float* wgt  = (const float*)d_in[1];
    const float* bias = (const float*)d_in[2];
    float* out = (float*)d_out;

    dim3 grid(16, 4, 16);   // (wx, strip, n) = 1024 blocks
    dim3 block(256, 1, 1);
    conv3x3_pipe2<<<grid, block, 0, stream>>>(x, wgt, bias, out);
}

// Round 15
// 276.599 us; speedup vs baseline: 1.2048x; 1.2048x over previous
//
#include <hip/hip_runtime.h>
#include <hip/hip_bf16.h>

// Conv2d NCHW, stride=1, pad=1, N=16, C=8, K=8, H=W=1024, 3x3, fp32 in/out.
// Round 15: register-direct staging with VOLATILE ASM loads (cannot be sunk
// by the compiler, unlike r9/r10's HIP loads) + exact counted vmcnt. No fp32
// LDS, no transpose pass: thread loads its 3 sites x 8 ci to regs (coalesced
// across lanes), converts, ds_write_b128 into the VERIFIED bf16 layout.
// LDS = bf double-buffer only (23KB) -> 4 blocks/CU. One barrier/iter.
// vmcnt ledger (per wave per iter): 24 asm loads + 8 stores, so at iter top
// queue = loads(cur)24 + stores(prev)8 + loads(next)24 = 56; vmcnt(32)
// drains exactly loads(cur), issued a FULL iteration earlier -> no stall.
// Static A/B reg banks via 2x-unrolled loop (rule 20). sched_barrier(0)
// after every asm wait (rule 18). Math identical to r13 (absmax 0.03125).

typedef __attribute__((ext_vector_type(8))) short short8;
typedef __attribute__((ext_vector_type(4))) float f32x4;

#define HH 1024
#define WW 1024
#define HWsz (1024*1024)
#define WB 64           // output cols per tile
#define HB 8            // output rows per tile
#define SROWS 10        // staged input rows per tile
#define UROW 72         // bf16 16B-units per row (w0-4 .. w0+67)
#define NIT 32          // h-tiles per block (strip = 256 rows)
#define NSITES (SROWS*UROW)   // 720

__device__ __forceinline__ int pk2(float a, float b) {
    __hip_bfloat162 h = __float22bfloat162_rn(make_float2(a, b));  // v_cvt_pk_bf16_f32
    return *reinterpret_cast<int*>(&h);
}
__device__ __forceinline__ unsigned short f2bf(float f) {
    unsigned u = __float_as_uint(f);
    return (unsigned short)((u + 0x7FFFu + ((u >> 16) & 1u)) >> 16);   // RNE
}

__global__ __launch_bounds__(256) void conv3x3_reg(
    const float* __restrict__ x,      // [16][8][1024][1024]
    const float* __restrict__ wgt,    // [8][8][3][3]
    const float* __restrict__ bias,   // [8]
    float* __restrict__ out)          // [16][8][1024][1024]
{
    __shared__ int4 bfA[NSITES];      // 11520 B each
    __shared__ int4 bfB[NSITES];

    const int tid  = threadIdx.x;
    const int lane = tid & 63;
    const int wv   = tid >> 6;        // wave 0..3
    const int l15  = lane & 15;
    const int ch   = lane >> 4;

    const int wx    = blockIdx.x;     // 0..15
    const int strip = blockIdx.y;     // 0..3
    const int n     = blockIdx.z;     // 0..15
    const int w0    = wx * WB;
    const int htbase = strip * (NIT * HB);    // strip*256

    const float* xn = x + (size_t)n * 8 * HWsz;
    // wave-uniform plane bases for asm loads
    const float* base0 = xn + 0 * (size_t)HWsz;
    const float* base1 = xn + 1 * (size_t)HWsz;
    const float* base2 = xn + 2 * (size_t)HWsz;
    const float* base3 = xn + 3 * (size_t)HWsz;
    const float* base4 = xn + 4 * (size_t)HWsz;
    const float* base5 = xn + 5 * (size_t)HWsz;
    const float* base6 = xn + 6 * (size_t)HWsz;
    const float* base7 = xn + 7 * (size_t)HWsz;

    // ---- tap -> bf16-LDS unit offsets (verified r7/r8/r11/r13) ----
    const int t0  = ch;                       // taps 0..3 (MFMA 0)
    const int kh0 = (t0 >= 3) ? 1 : 0;
    const int kw0 = t0 - 3 * kh0;
    const int t1  = 4 + ch;                   // taps 4..7 (MFMA 1)
    const int kh1 = (t1 >= 6) ? 2 : 1;
    const int kw1 = t1 - 3 * kh1;
    const int off0 = kh0 * UROW + kw0 + 3;
    const int off1 = kh1 * UROW + kw1 + 3;
    const int off2 = 2 * UROW + 2 + 3;        // tap 8 (2,2)

    // ---- weight B-fragments (verified) ----
    const int  coc = (l15 < 8) ? l15 : 7;
    const bool com = (l15 < 8);
    short8 b0, b1, b2;
    {
        const float* wp0 = wgt + coc * 72 + kh0 * 3 + kw0;
        const float* wp1 = wgt + coc * 72 + kh1 * 3 + kw1;
        const float* wp2 = wgt + coc * 72 + 2 * 3 + 2;
#pragma unroll
        for (int j = 0; j < 8; ++j) {
            b0[j] = (short)(com ? f2bf(wp0[j * 9]) : 0);
            b1[j] = (short)(com ? f2bf(wp1[j * 9]) : 0);
            b2[j] = (short)((com && ch == 0) ? f2bf(wp2[j * 9]) : 0);
        }
    }
    const float bv = com ? bias[l15] : 0.0f;

    // ---- per-thread site constants (3 sites: s = tid + j*256) ----
    int srow[3], gwc[3];
    bool wok[3], sv[3];
#pragma unroll
    for (int j = 0; j < 3; ++j) {
        const int s = tid + j * 256;
        sv[j]   = (s < NSITES);
        const int r = s / UROW;
        const int u = s - r * UROW;
        srow[j] = r;
        const int gwr = w0 - 4 + u;
        wok[j]  = ((unsigned)gwr < (unsigned)WW);
        gwc[j]  = (gwr < 0) ? 0 : ((gwr > WW - 1) ? WW - 1 : gwr);
    }

    float bkA[3][8], bkB[3][8];

    // issue 24 volatile asm loads for tile at htile into bank bk
#define LOADS(htile, bk)                                                     \
    {                                                                        \
        _Pragma("unroll")                                                    \
        for (int j = 0; j < 3; ++j) {                                        \
            const int gr  = (htile) - 1 + srow[j];                           \
            const int ghc = (gr < 0) ? 0 : ((gr > HH - 1) ? HH - 1 : gr);    \
            const unsigned voff = ((unsigned)(ghc * WW + gwc[j])) * 4u;      \
            asm volatile("global_load_dword %0, %8, %9\n\t"                  \
                         "global_load_dword %1, %8, %10\n\t"                 \
                         "global_load_dword %2, %8, %11\n\t"                 \
                         "global_load_dword %3, %8, %12\n\t"                 \
                         "global_load_dword %4, %8, %13\n\t"                 \
                         "global_load_dword %5, %8, %14\n\t"                 \
                         "global_load_dword %6, %8, %15\n\t"                 \
                         "global_load_dword %7, %8, %16"                     \
                         : "=v"(bk[j][0]), "=v"(bk[j][1]), "=v"(bk[j][2]),   \
                           "=v"(bk[j][3]), "=v"(bk[j][4]), "=v"(bk[j][5]),   \
                           "=v"(bk[j][6]), "=v"(bk[j][7])                    \
                         : "v"(voff), "s"(base0), "s"(base1), "s"(base2),    \
                           "s"(base3), "s"(base4), "s"(base5), "s"(base6),   \
                           "s"(base7)                                        \
                         : "memory");                                        \
        }                                                                    \
    }

    // convert bank -> bf16 LDS buffer (verified layout)
#define CONV(htile, bk, bfb)                                                 \
    {                                                                        \
        _Pragma("unroll")                                                    \
        for (int j = 0; j < 3; ++j) {                                        \
            if (sv[j]) {                                                     \
                const int gr = (htile) - 1 + srow[j];                        \
                const bool ok = ((unsigned)gr < (unsigned)HH) && wok[j];     \
                const float v0 = ok ? bk[j][0] : 0.0f;                       \
                const float v1 = ok ? bk[j][1] : 0.0f;                       \
                const float v2 = ok ? bk[j][2] : 0.0f;                       \
                const float v3 = ok ? bk[j][3] : 0.0f;                       \
                const float v4 = ok ? bk[j][4] : 0.0f;                       \
                const float v5 = ok ? bk[j][5] : 0.0f;                       \
                const float v6 = ok ? bk[j][6] : 0.0f;                       \
                const float v7 = ok ? bk[j][7] : 0.0f;                       \
                int4 pk;                                                     \
                pk.x = pk2(v0, v1);                                          \
                pk.y = pk2(v2, v3);                                          \
                pk.z = pk2(v4, v5);                                          \
                pk.w = pk2(v6, v7);                                          \
                (bfb)[tid + j * 256] = pk;                                   \
            }                                                                \
        }                                                                    \
    }

    // compute tile + store (verified r13 math)
#define BODY(htile, bsrc)                                                    \
    {                                                                        \
        f32x4 acc[2][4];                                                     \
        _Pragma("unroll")                                                    \
        for (int th = 0; th < 2; ++th)                                       \
            _Pragma("unroll")                                                \
            for (int wt = 0; wt < 4; ++wt) {                                 \
                acc[th][wt].x = bv; acc[th][wt].y = bv;                      \
                acc[th][wt].z = bv; acc[th][wt].w = bv;                      \
            }                                                                \
        _Pragma("unroll")                                                    \
        for (int th = 0; th < 2; ++th) {                                     \
            const int hl = wv * 2 + th;                                      \
            const int ub = hl * UROW + l15;                                  \
            _Pragma("unroll")                                                \
            for (int wt = 0; wt < 4; ++wt) {                                 \
                const int u = ub + wt * 16;                                  \
                short8 a0 = *reinterpret_cast<const short8*>(&(bsrc)[u + off0]); \
                short8 a1 = *reinterpret_cast<const short8*>(&(bsrc)[u + off1]); \
                short8 a2 = *reinterpret_cast<const short8*>(&(bsrc)[u + off2]); \
                f32x4 c = acc[th][wt];                                       \
                c = __builtin_amdgcn_mfma_f32_16x16x32_bf16(a0, b0, c, 0, 0, 0); \
                c = __builtin_amdgcn_mfma_f32_16x16x32_bf16(a1, b1, c, 0, 0, 0); \
                c = __builtin_amdgcn_mfma_f32_16x16x32_bf16(a2, b2, c, 0, 0, 0); \
                acc[th][wt] = c;                                             \
            }                                                                \
        }                                                                    \
        if (com) {                                                           \
            _Pragma("unroll")                                                \
            for (int th = 0; th < 2; ++th) {                                 \
                const int hl = wv * 2 + th;                                  \
                float* op = out + ((size_t)n * 8 + l15) * HWsz               \
                                + (size_t)((htile) + hl) * WW + w0 + ch * 4; \
                _Pragma("unroll")                                            \
                for (int wt = 0; wt < 4; ++wt)                               \
                    *reinterpret_cast<float4*>(op + wt * 16) =               \
                        *reinterpret_cast<const float4*>(&acc[th][wt]);      \
            }                                                                \
        }                                                                    \
    }

    // ---- prologue: issue tile-0 loads ----
    LOADS(htbase, bkA);

    for (int k = 0; k < NIT; k += 2) {
        // ======== even: consume A, prefetch into B ========
        {
            const int ht  = htbase + k * HB;
            LOADS(ht + HB, bkB);                       // tile k+1
            if (k == 0) {
                asm volatile("s_waitcnt vmcnt(24)" ::: "memory");
            } else {
                asm volatile("s_waitcnt vmcnt(32)" ::: "memory");
            }
            __builtin_amdgcn_sched_barrier(0);
            CONV(ht, bkA, bfA);
            asm volatile("s_waitcnt lgkmcnt(0)" ::: "memory");
            __builtin_amdgcn_sched_barrier(0);
            __builtin_amdgcn_s_barrier();
            BODY(ht, bfA);
        }
        // ======== odd: consume B, prefetch into A ========
        {
            const int ht  = htbase + (k + 1) * HB;
            int t2 = k + 2; if (t2 > NIT - 1) t2 = NIT - 1;   // clamp tail
            LOADS(htbase + t2 * HB, bkA);              // tile k+2
            asm volatile("s_waitcnt vmcnt(32)" ::: "memory");
            __builtin_amdgcn_sched_barrier(0);
            CONV(ht, bkB, bfB);
            asm volatile("s_waitcnt lgkmcnt(0)" ::: "memory");
            __builtin_amdgcn_sched_barrier(0);
            __builtin_amdgcn_s_barrier();
            BODY(ht, bfB);
        }
    }
#undef LOADS
#undef CONV
#undef BODY
}

extern "C" void kernel_launch(void* const* d_in, const int* in_sizes, int n_in,
                              void* d_out, int out_size, void* d_ws, size_t ws_size,
                              hipStream_t stream) {
    const float* x    = (const float*)d_in[0];
    const float* wgt  = (const float*)d_in[1];
    const float* bias = (const float*)d_in[2];
    float* out = (float*)d_out;

    dim3 grid(16, 4, 16);   // (wx, strip, n) = 1024 blocks, all resident
    dim3 block(256, 1, 1);
    conv3x3_reg<<<grid, block, 0, stream>>>(x, wgt, bias, out);
}

// Round 16
// 275.336 us; speedup vs baseline: 1.2104x; 1.0046x over previous
//
#include <hip/hip_runtime.h>
#include <hip/hip_bf16.h>

// Conv2d NCHW, stride=1, pad=1, N=16, C=8, K=8, H=W=1024, 3x3, fp32 in/out.
// Round 16 = r15 staging (volatile-asm loads + counted vmcnt, best so far)
// + TWO-ROW MFMA PACKING: K extended to 96 = 4 kh x 3 kw x 8 ci; B col co
// = taps kh0..2 for output row hl, col 8+co = same weights shifted one kh
// (kh1..3) = output row hl+1 FROM THE SAME A FRAGMENTS. All 16 N-columns
// used -> per wave per tile: 12 ds_read + 12 MFMA + 4 stores (was 24/24/8).
// Grid 2048 (NIT=16) -> 5-6 blocks/CU for stall-filling concurrency.

typedef __attribute__((ext_vector_type(8))) short short8;
typedef __attribute__((ext_vector_type(4))) float f32x4;

#define HH 1024
#define WW 1024
#define HWsz (1024*1024)
#define WB 64           // output cols per tile
#define HB 8            // output rows per tile
#define SROWS 10        // staged input rows per tile
#define UROW 72         // bf16 16B-units per row (w0-4 .. w0+67)
#define NIT 16          // h-tiles per block (strip = 128 rows)
#define NSITES (SROWS*UROW)   // 720

__device__ __forceinline__ int pk2(float a, float b) {
    __hip_bfloat162 h = __float22bfloat162_rn(make_float2(a, b));  // v_cvt_pk_bf16_f32
    return *reinterpret_cast<int*>(&h);
}
__device__ __forceinline__ unsigned short f2bf(float f) {
    unsigned u = __float_as_uint(f);
    return (unsigned short)((u + 0x7FFFu + ((u >> 16) & 1u)) >> 16);   // RNE
}

__global__ __launch_bounds__(256) void conv3x3_pack2(
    const float* __restrict__ x,      // [16][8][1024][1024]
    const float* __restrict__ wgt,    // [8][8][3][3]
    const float* __restrict__ bias,   // [8]
    float* __restrict__ out)          // [16][8][1024][1024]
{
    __shared__ int4 bfA[NSITES];      // 11520 B each
    __shared__ int4 bfB[NSITES];

    const int tid  = threadIdx.x;
    const int lane = tid & 63;
    const int wv   = tid >> 6;        // wave 0..3: output rows 2wv, 2wv+1
    const int l15  = lane & 15;
    const int ch   = lane >> 4;

    const int wx    = blockIdx.x;     // 0..15
    const int strip = blockIdx.y;     // 0..7
    const int n     = blockIdx.z;     // 0..15
    const int w0    = wx * WB;
    const int htbase = strip * (NIT * HB);    // strip*128

    const float* xn = x + (size_t)n * 8 * HWsz;
    const float* base0 = xn + 0 * (size_t)HWsz;
    const float* base1 = xn + 1 * (size_t)HWsz;
    const float* base2 = xn + 2 * (size_t)HWsz;
    const float* base3 = xn + 3 * (size_t)HWsz;
    const float* base4 = xn + 4 * (size_t)HWsz;
    const float* base5 = xn + 5 * (size_t)HWsz;
    const float* base6 = xn + 6 * (size_t)HWsz;
    const float* base7 = xn + 7 * (size_t)HWsz;

    // ---- K=96 slot map: s = kh*24 + kw*8 + ci; lane ch in MFMA t covers
    //      s = 32t+8ch .. +7  ->  one (kh,kw), ci=j ----
    const int s0 = 8 * ch,      kh0 = s0 / 24, kw0 = (s0 % 24) / 8;
    const int s1 = 32 + 8 * ch, kh1 = s1 / 24, kw1 = (s1 % 24) / 8;
    const int s2 = 64 + 8 * ch, kh2 = s2 / 24, kw2 = (s2 % 24) / 8;
    const int off0 = kh0 * UROW + kw0 + 3;
    const int off1 = kh1 * UROW + kw1 + 3;
    const int off2 = kh2 * UROW + kw2 + 3;

    // ---- B-fragments: col l15 = hi*8+co; col co -> row hl (kh eff = kh),
    //      col 8+co -> row hl+1 (kh eff = kh-1) ----
    const int hi  = l15 >> 3;         // 0: row hl, 1: row hl+1
    const int co8 = l15 & 7;
    short8 b0, b1, b2;
    {
        const int ke0 = kh0 - hi, ke1 = kh1 - hi, ke2 = kh2 - hi;
        const bool v0 = (ke0 >= 0) && (ke0 <= 2);
        const bool v1 = (ke1 >= 0) && (ke1 <= 2);
        const bool v2 = (ke2 >= 0) && (ke2 <= 2);
#pragma unroll
        for (int j = 0; j < 8; ++j) {
            b0[j] = (short)(v0 ? f2bf(wgt[co8 * 72 + j * 9 + ke0 * 3 + kw0]) : 0);
            b1[j] = (short)(v1 ? f2bf(wgt[co8 * 72 + j * 9 + ke1 * 3 + kw1]) : 0);
            b2[j] = (short)(v2 ? f2bf(wgt[co8 * 72 + j * 9 + ke2 * 3 + kw2]) : 0);
        }
    }
    const float bv = bias[co8];

    // ---- per-thread staging site constants (3 sites: s = tid + j*256) ----
    int srow[3], gwc[3];
    bool wok[3], sv[3];
#pragma unroll
    for (int j = 0; j < 3; ++j) {
        const int s = tid + j * 256;
        sv[j]   = (s < NSITES);
        const int r = s / UROW;
        const int u = s - r * UROW;
        srow[j] = r;
        const int gwr = w0 - 4 + u;
        wok[j]  = ((unsigned)gwr < (unsigned)WW);
        gwc[j]  = (gwr < 0) ? 0 : ((gwr > WW - 1) ? WW - 1 : gwr);
    }

    float bkA[3][8], bkB[3][8];

#define LOADS(htile, bk)                                                     \
    {                                                                        \
        _Pragma("unroll")                                                    \
        for (int j = 0; j < 3; ++j) {                                        \
            const int gr  = (htile) - 1 + srow[j];                           \
            const int ghc = (gr < 0) ? 0 : ((gr > HH - 1) ? HH - 1 : gr);    \
            const unsigned voff = ((unsigned)(ghc * WW + gwc[j])) * 4u;      \
            asm volatile("global_load_dword %0, %8, %9\n\t"                  \
                         "global_load_dword %1, %8, %10\n\t"                 \
                         "global_load_dword %2, %8, %11\n\t"                 \
                         "global_load_dword %3, %8, %12\n\t"                 \
                         "global_load_dword %4, %8, %13\n\t"                 \
                         "global_load_dword %5, %8, %14\n\t"                 \
                         "global_load_dword %6, %8, %15\n\t"                 \
                         "global_load_dword %7, %8, %16"                     \
                         : "=v"(bk[j][0]), "=v"(bk[j][1]), "=v"(bk[j][2]),   \
                           "=v"(bk[j][3]), "=v"(bk[j][4]), "=v"(bk[j][5]),   \
                           "=v"(bk[j][6]), "=v"(bk[j][7])                    \
                         : "v"(voff), "s"(base0), "s"(base1), "s"(base2),    \
                           "s"(base3), "s"(base4), "s"(base5), "s"(base6),   \
                           "s"(base7)                                        \
                         : "memory");                                        \
        }                                                                    \
    }

#define CONV(htile, bk, bfb)                                                 \
    {                                                                        \
        _Pragma("unroll")                                                    \
        for (int j = 0; j < 3; ++j) {                                        \
            if (sv[j]) {                                                     \
                const int gr = (htile) - 1 + srow[j];                        \
                const bool ok = ((unsigned)gr < (unsigned)HH) && wok[j];     \
                const float v0 = ok ? bk[j][0] : 0.0f;                       \
                const float v1 = ok ? bk[j][1] : 0.0f;                       \
                const float v2 = ok ? bk[j][2] : 0.0f;                       \
                const float v3 = ok ? bk[j][3] : 0.0f;                       \
                const float v4 = ok ? bk[j][4] : 0.0f;                       \
                const float v5 = ok ? bk[j][5] : 0.0f;                       \
                const float v6 = ok ? bk[j][6] : 0.0f;                       \
                const float v7 = ok ? bk[j][7] : 0.0f;                       \
                int4 pk;                                                     \
                pk.x = pk2(v0, v1);                                          \
                pk.y = pk2(v2, v3);                                          \
                pk.z = pk2(v4, v5);                                          \
                pk.w = pk2(v6, v7);                                          \
                (bfb)[tid + j * 256] = pk;                                   \
            }                                                                \
        }                                                                    \
    }

    // 2-row packed compute: 4 wt x 3 MFMA; all 16 D-cols valid.
#define BODY(htile, bsrc)                                                    \
    {                                                                        \
        f32x4 acc[4];                                                        \
        _Pragma("unroll")                                                    \
        for (int wt = 0; wt < 4; ++wt) {                                     \
            acc[wt].x = bv; acc[wt].y = bv; acc[wt].z = bv; acc[wt].w = bv;  \
        }                                                                    \
        const int ub = (2 * wv) * UROW + l15;                                \
        _Pragma("unroll")                                                    \
        for (int wt = 0; wt < 4; ++wt) {                                     \
            const int u = ub + wt * 16;                                      \
            short8 a0 = *reinterpret_cast<const short8*>(&(bsrc)[u + off0]); \
            short8 a1 = *reinterpret_cast<const short8*>(&(bsrc)[u + off1]); \
            short8 a2 = *reinterpret_cast<const short8*>(&(bsrc)[u + off2]); \
            f32x4 c = acc[wt];                                               \
            c = __builtin_amdgcn_mfma_f32_16x16x32_bf16(a0, b0, c, 0, 0, 0); \
            c = __builtin_amdgcn_mfma_f32_16x16x32_bf16(a1, b1, c, 0, 0, 0); \
            c = __builtin_amdgcn_mfma_f32_16x16x32_bf16(a2, b2, c, 0, 0, 0); \
            acc[wt] = c;                                                     \
        }                                                                    \
        float* op = out + ((size_t)n * 8 + co8) * HWsz                       \
                        + (size_t)((htile) + 2 * wv + hi) * WW + w0 + ch * 4;\
        _Pragma("unroll")                                                    \
        for (int wt = 0; wt < 4; ++wt)                                       \
            *reinterpret_cast<float4*>(op + wt * 16) =                       \
                *reinterpret_cast<const float4*>(&acc[wt]);                  \
    }

    // ---- prologue ----
    LOADS(htbase, bkA);

    for (int k = 0; k < NIT; k += 2) {
        // ======== even: consume A, prefetch into B ========
        {
            const int ht = htbase + k * HB;
            LOADS(ht + HB, bkB);                       // tile k+1
            if (k == 0) {
                asm volatile("s_waitcnt vmcnt(24)" ::: "memory");
            } else {
                asm volatile("s_waitcnt vmcnt(28)" ::: "memory");
            }
            __builtin_amdgcn_sched_barrier(0);
            CONV(ht, bkA, bfA);
            asm volatile("s_waitcnt lgkmcnt(0)" ::: "memory");
            __builtin_amdgcn_sched_barrier(0);
            __builtin_amdgcn_s_barrier();
            BODY(ht, bfA);
        }
        // ======== odd: consume B, prefetch into A ========
        {
            const int ht = htbase + (k + 1) * HB;
            int t2 = k + 2; if (t2 > NIT - 1) t2 = NIT - 1;   // clamp tail
            LOADS(htbase + t2 * HB, bkA);              // tile k+2
            asm volatile("s_waitcnt vmcnt(28)" ::: "memory");
            __builtin_amdgcn_sched_barrier(0);
            CONV(ht, bkB, bfB);
            asm volatile("s_waitcnt lgkmcnt(0)" ::: "memory");
            __builtin_amdgcn_sched_barrier(0);
            __builtin_amdgcn_s_barrier();
            BODY(ht, bfB);
        }
    }
#undef LOADS
#undef CONV
#undef BODY
}

extern "C" void kernel_launch(void* const* d_in, const int* in_sizes, int n_in,
                              void* d_out, int out_size, void* d_ws, size_t ws_size,
                              hipStream_t stream) {
    const float* x    = (const float*)d_in[0];
    const float* wgt  = (const float*)d_in[1];
    const float* bias = (const float*)d_in[2];
    float* out = (float*)d_out;

    dim3 grid(16, 8, 16);   // (wx, strip, n) = 2048 blocks
    dim3 block(256, 1, 1);
    conv3x3_pack2<<<grid, block, 0, stream>>>(x, wgt, bias, out);
}